// Round 6
// baseline (529.307 us; speedup 1.0000x reference)
//
#include <hip/hip_runtime.h>

#define Bn 512
#define Ln 2048
#define Kn 19
#define NEGV (-1000.0f)
#define START_IDn 17
#define PAD_IDn 18
#define SEG 64               // checkpoint / staging segment (steps)
#define PBYTES 79691776u     // 512*2048*19*4

// ---------------------------------------------------------------------------
// R11: split kernels (fusion abandoned: R9/R10 co-residency tax unexplained).
// fwd chain rebuilt VALU-only: dp[0..15] on lanes 0-15, broadcast by the
// R8-validated 15-mov XOR-DPP butterfly (quad_perm ^1/^2/^3, half_mirror ^7,
// mirror ^15, compositions -> all 16 masks). dp[16..18] ride a secondary
// accumulator on lanes 0-2, wave-broadcast via 3 v_readlane SGPRs. No DS op
// in the dependency chain (R8's swizzle-stall removed); emissions come from
// the R5-proven LDS double-buffer (prefetchable ds_read, off-chain); no
// per-step global loads (R8's other flaw). Same add pairings + exact max
// => bit-identical DP => rec argmax unchanged. rec/bwd verbatim from R5.
// ---------------------------------------------------------------------------

// rec per-step core (unchanged): dp read from LDS, occupancy hides latency.
#define DP_CORE(BASE)                                                          \
    float4 q0 = *(const float4*)((BASE) + 0);                                  \
    float4 q1 = *(const float4*)((BASE) + 4);                                  \
    float4 q2 = *(const float4*)((BASE) + 8);                                  \
    float4 q3 = *(const float4*)((BASE) + 12);                                 \
    float4 q4 = *(const float4*)((BASE) + 16); /* .w junk, unused */           \
    float cand[Kn];                                                            \
    cand[0]  = q0.x + Trow[0];  cand[1]  = q0.y + Trow[1];                     \
    cand[2]  = q0.z + Trow[2];  cand[3]  = q0.w + Trow[3];                     \
    cand[4]  = q1.x + Trow[4];  cand[5]  = q1.y + Trow[5];                     \
    cand[6]  = q1.z + Trow[6];  cand[7]  = q1.w + Trow[7];                     \
    cand[8]  = q2.x + Trow[8];  cand[9]  = q2.y + Trow[9];                     \
    cand[10] = q2.z + Trow[10]; cand[11] = q2.w + Trow[11];                    \
    cand[12] = q3.x + Trow[12]; cand[13] = q3.y + Trow[13];                    \
    cand[14] = q3.z + Trow[14]; cand[15] = q3.w + Trow[15];                    \
    cand[16] = q4.x + Trow[16]; cand[17] = q4.y + Trow[17];                    \
    cand[18] = q4.z + Trow[18];                                                \
    float m0 = fmaxf(fmaxf(cand[0],  cand[1]),  cand[2]);                      \
    float m1 = fmaxf(fmaxf(cand[3],  cand[4]),  cand[5]);                      \
    float m2 = fmaxf(fmaxf(cand[6],  cand[7]),  cand[8]);                      \
    float m3 = fmaxf(fmaxf(cand[9],  cand[10]), cand[11]);                     \
    float m4 = fmaxf(fmaxf(cand[12], cand[13]), cand[14]);                     \
    float m5 = fmaxf(fmaxf(cand[15], cand[16]), cand[17]);                     \
    float n0 = fmaxf(fmaxf(m0, m1), m2);                                       \
    float n1 = fmaxf(fmaxf(m3, m4), cand[18]);                                 \
    float best = fmaxf(fmaxf(n0, n1), m5);

// DPP permute: result[lane] = x[perm(lane)], all rows/banks, no bound ctrl.
#define DPPF(x, ctrl) (__int_as_float(__builtin_amdgcn_update_dpp(            \
    __float_as_int(x), __float_as_int(x), (ctrl), 0xF, 0xF, false)))

// 19-way exact-max tree over butterfly candidates v0..vf (+TT[m]) and the
// three scalar-broadcast tags (+G*). Exact max => order-free => bit-exact
// vs reference regardless of grouping.
#define DTREE(RES, TT, G0_, G1_, G2_)                                          \
    {                                                                          \
      float d0 = v0 + TT[0],  d1 = v1 + TT[1],  d2 = v2 + TT[2];               \
      float d3 = v3 + TT[3],  d4 = v4 + TT[4],  d5 = v5 + TT[5];               \
      float d6 = v6 + TT[6],  d7 = v7 + TT[7],  d8 = v8 + TT[8];               \
      float d9 = v9 + TT[9],  d10 = va + TT[10], d11 = vb + TT[11];            \
      float d12 = vc + TT[12], d13 = vd + TT[13], d14 = ve + TT[14];           \
      float d15 = vf + TT[15];                                                 \
      float x16 = s16 + (G0_), x17 = s17 + (G1_), x18 = s18 + (G2_);           \
      float m0 = fmaxf(fmaxf(d0, d1), d2);                                     \
      float m1 = fmaxf(fmaxf(d3, d4), d5);                                     \
      float m2 = fmaxf(fmaxf(d6, d7), d8);                                     \
      float m3 = fmaxf(fmaxf(d9, d10), d11);                                   \
      float m4 = fmaxf(fmaxf(d12, d13), d14);                                  \
      float m5 = fmaxf(fmaxf(d15, x16), x17);                                  \
      float n0 = fmaxf(fmaxf(m0, m1), m2);                                     \
      float n1 = fmaxf(fmaxf(m3, m4), m5);                                     \
      RES = fmaxf(fmaxf(n0, n1), x18);                                         \
    }

// One DP step, VALU-only chain. v_m[lane] = A[lane^m] (16-lane-local):
//   ^1=quad_perm 0xB1, ^2=0x4E, ^3=0x1B, ^7=half_mirror 0x141,
//   ^15=mirror 0x140, compositions give the rest (R8 HW-validated).
#define FSTEP(U, MASKED)                                                       \
  {                                                                            \
    const float v0 = A;                                                        \
    const float v1 = DPPF(A, 0xB1);                                            \
    const float v2 = DPPF(A, 0x4E);                                            \
    const float v3 = DPPF(A, 0x1B);                                            \
    const float v7 = DPPF(A, 0x141);                                           \
    const float v6 = DPPF(v7, 0xB1);                                           \
    const float v5 = DPPF(v7, 0x4E);                                           \
    const float v4 = DPPF(v7, 0x1B);                                           \
    const float vf = DPPF(A, 0x140);                                           \
    const float ve = DPPF(vf, 0xB1);                                           \
    const float vd = DPPF(vf, 0x4E);                                           \
    const float vc = DPPF(vf, 0x1B);                                           \
    const float v8 = DPPF(vf, 0x141);                                          \
    const float v9 = DPPF(v8, 0xB1);                                           \
    const float va = DPPF(v8, 0x4E);                                           \
    const float vb = DPPF(v8, 0x1B);                                           \
    float bp, bs;                                                              \
    DTREE(bp, Tp, Gp0, Gp1, Gp2)                                               \
    DTREE(bs, Ts, Gs0, Gs1, Gs2)                                               \
    const float e  = ebl[(tt + (U)) * Kn + jr];                                \
    const float e2 = ebl[(tt + (U)) * Kn + o2];                                \
    const float nd  = bp + e;                                                  \
    const float nd2 = bs + e2;                                                 \
    if (MASKED) {                                                              \
      const int t = t0 + tt + (U);                                             \
      A   = (t < len) ? nd  : A;                                               \
      sec = (t < len) ? nd2 : sec;                                             \
    } else {                                                                   \
      A   = nd;                                                                \
      sec = nd2;                                                               \
    }                                                                          \
    s16 = __uint_as_float((unsigned)__builtin_amdgcn_readlane(                 \
              (int)__float_as_uint(sec), 0));                                  \
    s17 = __uint_as_float((unsigned)__builtin_amdgcn_readlane(                 \
              (int)__float_as_uint(sec), 1));                                  \
    s18 = __uint_as_float((unsigned)__builtin_amdgcn_readlane(                 \
              (int)__float_as_uint(sec), 2));                                  \
  }

// ---------------------------------------------------------------------------
__global__ __launch_bounds__(64, 1) void crf_fwd(
    const float* __restrict__ P, const float* __restrict__ T,
    const int* __restrict__ mask, float* __restrict__ dpck,
    float* __restrict__ dpfin, int* __restrict__ lens)
{
    const int lane = threadIdx.x;
    const int jr = lane & 15;                  // butterfly position / tag 0..15
    const int b = blockIdx.x;                  // 1 batch per wave64
    const int o2 = 16 + ((jr < 3) ? jr : 2);   // secondary tag (lanes 0-2 real)

    // butterfly-indexed transition rows: Tp[m] = T[jr][jr^m], Ts for tag o2
    float Tp[16], Ts[16];
#pragma unroll
    for (int m = 0; m < 16; ++m) {
        Tp[m] = T[jr * Kn + (jr ^ m)];
        Ts[m] = T[o2 * Kn + (jr ^ m)];
    }
    const float Gp0 = T[jr * Kn + 16], Gp1 = T[jr * Kn + 17], Gp2 = T[jr * Kn + 18];
    const float Gs0 = T[o2 * Kn + 16], Gs1 = T[o2 * Kn + 17], Gs2 = T[o2 * Kn + 18];

    // length = popcount of contiguous-prefix mask row (64 lanes x int4 x 8)
    const int* mrow = mask + (size_t)b * Ln;
    int sum = 0;
#pragma unroll
    for (int j2 = 0; j2 < Ln / 256; ++j2) {
        int4 v = *(const int4*)(mrow + j2 * 256 + lane * 4);
        sum += v.x + v.y + v.z + v.w;
    }
#pragma unroll
    for (int k = 1; k < 64; k <<= 1) sum += __shfl_xor(sum, k, 64);
    const int len = __builtin_amdgcn_readfirstlane(sum);   // wave-uniform
    if (lane == 0) lens[b] = len;
    const int mlen = (len + (SEG - 1)) & ~(SEG - 1);

    // DP state: A = dp[jr] (lanes 0-15 real); sec = dp[16+jr] (lanes 0-2 real)
    float A = NEGV;
    float sec = (jr == 1) ? 0.0f : NEGV;       // tag 17 == START
    float s16, s17, s18;
    s16 = __uint_as_float((unsigned)__builtin_amdgcn_readlane((int)__float_as_uint(sec), 0));
    s17 = __uint_as_float((unsigned)__builtin_amdgcn_readlane((int)__float_as_uint(sec), 1));
    s18 = __uint_as_float((unsigned)__builtin_amdgcn_readlane((int)__float_as_uint(sec), 2));

    // emissions double-buffer: SEG*19 = 1216 floats used, 1280 staged
    __shared__ float ebuf[2][1280];

    const unsigned bbyte = (unsigned)b * (Ln * Kn * 4u);
    const unsigned limit = PBYTES - 16;
    const char* Pc = (const char*)P;
    float4 r[5];

#define STAGE_LOAD(ci)                                                         \
    { unsigned base_ = bbyte + (unsigned)(ci) * 4864u + ((unsigned)lane << 4); \
      _Pragma("unroll")                                                        \
      for (int i_ = 0; i_ < 5; ++i_) {                                         \
          unsigned o_ = base_ + (unsigned)i_ * 1024u;                          \
          if (o_ > limit) o_ = limit;                                          \
          r[i_] = *(const float4*)(Pc + o_);                                   \
      } }
#define STAGE_WRITE(nb)                                                        \
    { float* d_ = &ebuf[nb][(unsigned)lane << 2];                              \
      _Pragma("unroll")                                                        \
      for (int i_ = 0; i_ < 5; ++i_) *(float4*)(d_ + i_ * 256) = r[i_]; }

    int buf = 0;
    STAGE_LOAD(0);
    STAGE_WRITE(0);

    for (int t0 = 0; t0 < mlen; t0 += SEG) {
        // checkpoint: DP entering step t0 (includes initial DP at t0=0)
        {
            const unsigned ck = ((unsigned)b * 32u + (unsigned)(t0 >> 6)) * (unsigned)Kn;
            if (lane < 16) dpck[ck + (unsigned)jr] = A;
            if (lane < 3)  dpck[ck + 16u + (unsigned)lane] = sec;
        }
        STAGE_LOAD((t0 >> 6) + 1);       // prefetch next segment's emissions
        const float* ebl = &ebuf[buf][0];

        if (t0 + SEG <= len) {
            // fast path: every step strictly below len — no mask select
            for (int tt = 0; tt < SEG; tt += 8) {
                FSTEP(0, 0) FSTEP(1, 0) FSTEP(2, 0) FSTEP(3, 0)
                FSTEP(4, 0) FSTEP(5, 0) FSTEP(6, 0) FSTEP(7, 0)
            }
        } else {
            for (int tt = 0; tt < SEG; tt += 8) {
                FSTEP(0, 1) FSTEP(1, 1) FSTEP(2, 1) FSTEP(3, 1)
                FSTEP(4, 1) FSTEP(5, 1) FSTEP(6, 1) FSTEP(7, 1)
            }
        }
        STAGE_WRITE(buf ^ 1);
        buf ^= 1;
    }
    if (lane < 16) dpfin[b * Kn + jr] = A;
    if (lane < 3)  dpfin[b * Kn + 16 + lane] = sec;
#undef STAGE_LOAD
#undef STAGE_WRITE
}

// ---------------------------------------------------------------------------
// Recompute backpointers (R5-proven, unchanged): task = (batch, segment);
// 32-lane half-wave per task, 8 tasks per 256-thread block. High occupancy
// hides all latencies; per-step math is bit-identical to crf_fwd (same add
// pairs, exact max), so argmax reproduces the exact backpointers.
// ---------------------------------------------------------------------------
__global__ __launch_bounds__(256) void crf_rec(
    const float* __restrict__ P, const float* __restrict__ T,
    const float* __restrict__ dpck, const int* __restrict__ lens,
    unsigned char* __restrict__ choice)
{
    const int tid = threadIdx.x;
    const int halfid = tid >> 5;
    const int c = tid & 31;
    const int cc = (c < Kn) ? c : (Kn - 1);
    const int task = blockIdx.x * 8 + halfid;   // < 16384
    const int b = task >> 5;
    const int seg = task & 31;
    const int t0 = seg * SEG;
    const int len = lens[b];
    if (t0 >= len) return;                      // rows never read by backtrace

    __shared__ float dp[8][32];
    __shared__ __align__(16) unsigned char cbuf[8][SEG * Kn];  // 8 x 1216

    float Trow[Kn];
#pragma unroll
    for (int p = 0; p < Kn; ++p) Trow[p] = T[cc * Kn + p];

    float mydp = (c < Kn) ? dpck[((unsigned)b * 32u + (unsigned)seg) * (unsigned)Kn + (unsigned)c]
                          : NEGV;
    dp[halfid][c] = mydp;

    const float* prow = P + (size_t)b * Ln * Kn + (size_t)t0 * Kn;

    // rolling emission prefetch (depth 8)
    float eb[8];
#pragma unroll
    for (int u = 0; u < 8; ++u) eb[u] = prow[u * Kn + cc];

    for (int tt = 0; tt < SEG; tt += 8) {
#pragma unroll
        for (int u = 0; u < 8; ++u) {
            const int t = t0 + tt + u;
            const float e = eb[u];
            const float* base_ = &dp[halfid][0];
            DP_CORE(base_)
            float nd = best + e;
            mydp = (t < len) ? nd : mydp;
            dp[halfid][c] = mydp;

            // first-index argmax (jnp.argmax tie-break), exact equality
            int arg = Kn - 1;
#pragma unroll
            for (int p = Kn - 2; p >= 0; --p)
                arg = (cand[p] == best) ? p : arg;
            if (c < Kn) cbuf[halfid][(tt + u) * Kn + c] = (unsigned char)arg;

            // prefetch emission for local step tt+u+8 (clamped in-bounds)
            int tn = tt + u + 8;
            int tloc = (t0 + tn < Ln) ? tn : (Ln - 1 - t0);
            eb[u] = prow[tloc * Kn + cc];
        }
    }
    // bulk flush this segment's backpointers (steps >= len garbage, unread)
    {
        const int4* s = (const int4*)&cbuf[halfid][0];
        int4* d = (int4*)(choice + (size_t)b * Ln * Kn + (size_t)t0 * Kn);
        for (int i = c; i < (SEG * Kn) / 16; i += 32) d[i] = s[i];
    }
}

// ---------------------------------------------------------------------------
// Backtrace: unchanged (exact integer function-composition scan).
// ---------------------------------------------------------------------------
__global__ __launch_bounds__(384, 1) void crf_bwd(
    const float* __restrict__ T, const unsigned char* __restrict__ choice,
    const float* __restrict__ dpfin, const int* __restrict__ lens,
    int* __restrict__ out)
{
    __shared__ unsigned char comp[Ln * Kn];   // 38912 B
    __shared__ int vchain[17];
    __shared__ int s_last, s_len;

    const int b = blockIdx.x;
    const int tid = threadIdx.x;

    {
        const int4* src = (const int4*)(choice + (size_t)b * Ln * Kn);
        int4* dst = (int4*)comp;
        for (int i = tid; i < (Ln * Kn) / 16; i += 384) dst[i] = src[i];
    }
    if (tid == 0) {
        s_len = lens[b];
        float bestv = dpfin[b * Kn + 0] + T[PAD_IDn * Kn + 0];
        int bl = 0;
        for (int ci = 1; ci < Kn; ++ci) {
            float v = dpfin[b * Kn + ci] + T[PAD_IDn * Kn + ci];
            if (v > bestv) { bestv = v; bl = ci; }
        }
        s_last = bl;
    }
    __syncthreads();
    const int len = s_len;

    // Phase 1: suffix-compose within each 128-step chunk, in place.
    {
        const int wv = tid >> 6;
        const int lane = tid & 63;
        const int ch = wv * 3 + lane / Kn;
        const int c = lane % Kn;
        if (lane < 3 * Kn && ch < 16) {
            int cur = c;
            const int tb = ch * 128 + 127;
            for (int i = 0; i < 128; ++i) {
                const int t = tb - i;
                int nv = comp[t * Kn + cur];   // cur <= 18 always: in-bounds
                cur = (t < len) ? nv : cur;
                comp[t * Kn + c] = cur;
            }
        }
    }
    __syncthreads();

    // Phase 2: chunk-boundary chain
    if (tid == 0) {
        int v = s_last;
        vchain[16] = v;
        for (int ch = 15; ch >= 0; --ch) {
            v = comp[ch * 128 * Kn + v];
            vchain[ch] = v;
        }
    }
    __syncthreads();

    // Phase 3: emit path
    const int last = s_last;
    int* orow = out + (size_t)b * Ln;
    for (int t = tid; t < Ln; t += 384) {
        int val;
        if (t >= len) {
            val = -1;
        } else if (t == Ln - 1) {
            val = last;
        } else {
            const int tp = t + 1;
            const int vc = vchain[(tp >> 7) + 1];
            val = comp[tp * Kn + vc];
        }
        orow[t] = val;
    }
}

// ---------------------------------------------------------------------------
extern "C" void kernel_launch(void* const* d_in, const int* in_sizes, int n_in,
                              void* d_out, int out_size, void* d_ws, size_t ws_size,
                              hipStream_t stream)
{
    const float* P    = (const float*)d_in[0];
    const float* T    = (const float*)d_in[1];
    const int*   mask = (const int*)d_in[2];
    int* out = (int*)d_out;

    // workspace layout — identical proven footprint (R1-R5)
    const size_t choice_bytes = (size_t)Bn * Ln * Kn;            // 19,922,944
    unsigned char* choice = (unsigned char*)d_ws;
    float* dpfin = (float*)((char*)d_ws + choice_bytes);         // 38,912 B
    int* lens = (int*)((char*)d_ws + choice_bytes + (size_t)Bn * Kn * 4);

    // dpck (1,245,184 B) lives in d_out (4 MB): written by crf_fwd, read by
    // crf_rec, then d_out is fully overwritten by crf_bwd. Stream-ordered.
    float* dpck = (float*)((char*)d_out + 2 * 1024 * 1024);

    crf_fwd<<<Bn, 64, 0, stream>>>(P, T, mask, dpck, dpfin, lens);
    crf_rec<<<(Bn * 32) / 8, 256, 0, stream>>>(P, T, dpck, lens, choice);
    crf_bwd<<<Bn, 384, 0, stream>>>(T, choice, dpfin, lens, out);
}

// Round 7
// 525.726 us; speedup vs baseline: 1.0068x; 1.0068x over previous
//
#include <hip/hip_runtime.h>

#define Bn 512
#define Ln 2048
#define Kn 19
#define NEGV (-1000.0f)
#define START_IDn 17
#define PAD_IDn 18
#define SEG 64               // checkpoint / staging segment (steps)
#define PBYTES 79691776u     // 512*2048*19*4

// ---------------------------------------------------------------------------
// R12: dual-phase software-pipelined R5 core. One wave, two batch-groups at
// opposite pipeline phases: P = lanes 0-31 (batch 2*blk), Q = lanes 32-63
// (batch 2*blk+1). Per step: treeP -> ds_write dpP -> reload P's float4s;
// then treeQ -> ds_write dpQ -> reload Q's. Each group's ~75cy of VALU sits
// inside the other's ~120cy LDS round-trip, which R5 left exposed (R6-R11
// showed every cross-lane alternative is worse; the only remaining lever is
// overlap). Distinct __shared__ arrays (no alias) + per-wave DS ordering
// make it sync-free; compiler emits counted lgkmcnt. Same add pairs + exact
// max tree => bit-identical DP => rec argmax unchanged. Worst case the
// compiler serializes back to R5's 280cy/step (downside-bounded).
// rec/bwd verbatim from the proven round-0 kernels.
// ---------------------------------------------------------------------------

// rec per-step core (unchanged): dp read from LDS, occupancy hides latency.
#define DP_CORE(BASE)                                                          \
    float4 q0 = *(const float4*)((BASE) + 0);                                  \
    float4 q1 = *(const float4*)((BASE) + 4);                                  \
    float4 q2 = *(const float4*)((BASE) + 8);                                  \
    float4 q3 = *(const float4*)((BASE) + 12);                                 \
    float4 q4 = *(const float4*)((BASE) + 16); /* .w junk, unused */           \
    float cand[Kn];                                                            \
    cand[0]  = q0.x + Trow[0];  cand[1]  = q0.y + Trow[1];                     \
    cand[2]  = q0.z + Trow[2];  cand[3]  = q0.w + Trow[3];                     \
    cand[4]  = q1.x + Trow[4];  cand[5]  = q1.y + Trow[5];                     \
    cand[6]  = q1.z + Trow[6];  cand[7]  = q1.w + Trow[7];                     \
    cand[8]  = q2.x + Trow[8];  cand[9]  = q2.y + Trow[9];                     \
    cand[10] = q2.z + Trow[10]; cand[11] = q2.w + Trow[11];                    \
    cand[12] = q3.x + Trow[12]; cand[13] = q3.y + Trow[13];                    \
    cand[14] = q3.z + Trow[14]; cand[15] = q3.w + Trow[15];                    \
    cand[16] = q4.x + Trow[16]; cand[17] = q4.y + Trow[17];                    \
    cand[18] = q4.z + Trow[18];                                                \
    float m0 = fmaxf(fmaxf(cand[0],  cand[1]),  cand[2]);                      \
    float m1 = fmaxf(fmaxf(cand[3],  cand[4]),  cand[5]);                      \
    float m2 = fmaxf(fmaxf(cand[6],  cand[7]),  cand[8]);                      \
    float m3 = fmaxf(fmaxf(cand[9],  cand[10]), cand[11]);                     \
    float m4 = fmaxf(fmaxf(cand[12], cand[13]), cand[14]);                     \
    float m5 = fmaxf(fmaxf(cand[15], cand[16]), cand[17]);                     \
    float n0 = fmaxf(fmaxf(m0, m1), m2);                                       \
    float n1 = fmaxf(fmaxf(m3, m4), cand[18]);                                 \
    float best = fmaxf(fmaxf(n0, n1), m5);

// One phase-step: tree from carried float4 regs RA..RE, select, write own dp,
// immediately re-issue the 5 uniform-address b128 loads for the next step
// (they retire during the OTHER phase's tree). EBL = this group's emission
// buffer base; DPW = this group's write slot; RBASE = this group's read base.
#define PH_STEP(U, MASKED, MYDP, RA, RB, RC, RD, RE, EBL, DPW, RBASE)          \
  {                                                                            \
    float cand[Kn];                                                            \
    cand[0]  = RA.x + Trow[0];  cand[1]  = RA.y + Trow[1];                     \
    cand[2]  = RA.z + Trow[2];  cand[3]  = RA.w + Trow[3];                     \
    cand[4]  = RB.x + Trow[4];  cand[5]  = RB.y + Trow[5];                     \
    cand[6]  = RB.z + Trow[6];  cand[7]  = RB.w + Trow[7];                     \
    cand[8]  = RC.x + Trow[8];  cand[9]  = RC.y + Trow[9];                     \
    cand[10] = RC.z + Trow[10]; cand[11] = RC.w + Trow[11];                    \
    cand[12] = RD.x + Trow[12]; cand[13] = RD.y + Trow[13];                    \
    cand[14] = RD.z + Trow[14]; cand[15] = RD.w + Trow[15];                    \
    cand[16] = RE.x + Trow[16]; cand[17] = RE.y + Trow[17];                    \
    cand[18] = RE.z + Trow[18];                                                \
    float m0 = fmaxf(fmaxf(cand[0],  cand[1]),  cand[2]);                      \
    float m1 = fmaxf(fmaxf(cand[3],  cand[4]),  cand[5]);                      \
    float m2 = fmaxf(fmaxf(cand[6],  cand[7]),  cand[8]);                      \
    float m3 = fmaxf(fmaxf(cand[9],  cand[10]), cand[11]);                     \
    float m4 = fmaxf(fmaxf(cand[12], cand[13]), cand[14]);                     \
    float m5 = fmaxf(fmaxf(cand[15], cand[16]), cand[17]);                     \
    float n0 = fmaxf(fmaxf(m0, m1), m2);                                       \
    float n1 = fmaxf(fmaxf(m3, m4), cand[18]);                                 \
    float best = fmaxf(fmaxf(n0, n1), m5);                                     \
    const float e = (EBL)[(tt + (U)) * Kn + cc];                               \
    float nd = best + e;                                                       \
    if (MASKED) {                                                              \
      const int t = t0 + tt + (U);                                             \
      MYDP = (t < len) ? nd : MYDP;                                            \
    } else {                                                                   \
      MYDP = nd;                                                               \
    }                                                                          \
    (DPW)[lane] = MYDP;                                                        \
    RA = *(const float4*)((RBASE) + 0);                                        \
    RB = *(const float4*)((RBASE) + 4);                                        \
    RC = *(const float4*)((RBASE) + 8);                                        \
    RD = *(const float4*)((RBASE) + 12);                                       \
    RE = *(const float4*)((RBASE) + 16);                                       \
  }

// ---------------------------------------------------------------------------
__global__ __launch_bounds__(64, 1) void crf_fwd(
    const float* __restrict__ P, const float* __restrict__ T,
    const int* __restrict__ mask, float* __restrict__ dpck,
    float* __restrict__ dpfin, int* __restrict__ lens)
{
    const int lane = threadIdx.x;
    const int half = lane >> 5;
    const int c = lane & 31;
    const int b = blockIdx.x * 2 + half;       // this lane's own batch
    const int cc = (c < Kn) ? c : (Kn - 1);

    float Trow[Kn];                            // serves BOTH phases: in phase
#pragma unroll                                 // P lanes 0-31 are live (tag=c),
    for (int p = 0; p < Kn; ++p)               // in phase Q lanes 32-63 are.
        Trow[p] = T[cc * Kn + p];

    // length = popcount of contiguous-prefix mask row (per half, R5-exact)
    const int* mrow = mask + (size_t)b * Ln;
    int sum = 0;
#pragma unroll
    for (int j = 0; j < Ln / 128; ++j) {
        int4 v = *(const int4*)(mrow + j * 128 + c * 4);
        sum += v.x + v.y + v.z + v.w;
    }
#pragma unroll
    for (int k = 1; k < 32; k <<= 1) sum += __shfl_xor(sum, k, 64);
    const int len = sum;                       // per-lane: own half's length
    if (c == 0) lens[b] = len;
    const int lenO = __shfl_xor(len, 32, 64);
    int maxlen = len > lenO ? len : lenO;
    int lmin = len < lenO ? len : lenO;
    lmin = __builtin_amdgcn_readfirstlane(lmin);
    int mlen = (maxlen + (SEG - 1)) & ~(SEG - 1);
    mlen = __builtin_amdgcn_readfirstlane(mlen);

    // --- LDS: two independent dp arrays (one per phase-group) + staging ----
    __shared__ float dpP[64];                  // P: lanes 0-18 real, rest junk
    __shared__ float dpQ[64];                  // Q: lanes 32-50 real
    __shared__ float ebuf[2][2][1280];         // [buf][half]; 1216 used + pad

    // both registers defined on all lanes (garbage on the inactive half)
    float mydpP = (c == START_IDn) ? 0.0f : NEGV;
    float mydpQ = mydpP;
    dpP[lane] = mydpP;
    dpQ[lane] = mydpQ;

    const unsigned bbyte = (unsigned)b * (Ln * Kn * 4u);
    const unsigned limit = PBYTES - 16;
    const char* Pc = (const char*)P;
    float4 r[10];

#define STAGE_LOAD(ci)                                                         \
    { unsigned base_ = bbyte + (unsigned)(ci) * 4864u + ((unsigned)c << 4);    \
      _Pragma("unroll")                                                        \
      for (int i_ = 0; i_ < 10; ++i_) {                                        \
          unsigned o_ = base_ + (unsigned)i_ * 512u;                           \
          if (o_ > limit) o_ = limit;                                          \
          r[i_] = *(const float4*)(Pc + o_);                                   \
      } }
#define STAGE_WRITE(nb)                                                        \
    { float* d_ = &ebuf[nb][half][(unsigned)c << 2];                           \
      _Pragma("unroll")                                                        \
      for (int i_ = 0; i_ < 10; ++i_) *(float4*)(d_ + i_ * 128) = r[i_]; }

    int buf = 0;
    STAGE_LOAD(0);
    STAGE_WRITE(0);

    // prime the carried operand vectors (reads queue behind the init writes)
    const float* rbP = &dpP[0];                // uniform addr: dp tags 0..19
    const float* rbQ = &dpQ[32];               // uniform addr: dp tags 0..19
    float4 pA = *(const float4*)(rbP + 0),  pB = *(const float4*)(rbP + 4);
    float4 pC = *(const float4*)(rbP + 8),  pD = *(const float4*)(rbP + 12);
    float4 pE = *(const float4*)(rbP + 16);
    float4 qA = *(const float4*)(rbQ + 0),  qB = *(const float4*)(rbQ + 4);
    float4 qC = *(const float4*)(rbQ + 8),  qD = *(const float4*)(rbQ + 12);
    float4 qE = *(const float4*)(rbQ + 16);

    for (int t0 = 0; t0 < mlen; t0 += SEG) {
        // checkpoint: DP entering step t0 (both batches, bit-exact registers)
        if (c < Kn) {
            const float v = half ? mydpQ : mydpP;
            dpck[((unsigned)b * 32u + (unsigned)(t0 >> 6)) * (unsigned)Kn + (unsigned)c] = v;
        }
        STAGE_LOAD((t0 >> 6) + 1);       // prefetch next segment's emissions
        const float* eblP = &ebuf[buf][0][0];
        const float* eblQ = &ebuf[buf][1][0];

        if (t0 + SEG <= lmin) {
            // fast path: all steps below both lengths — no mask selects
            for (int tt = 0; tt < SEG; tt += 8) {
#pragma unroll
                for (int u = 0; u < 8; ++u) {
                    PH_STEP(u, 0, mydpP, pA, pB, pC, pD, pE, eblP, dpP, rbP)
                    PH_STEP(u, 0, mydpQ, qA, qB, qC, qD, qE, eblQ, dpQ, rbQ)
                }
            }
        } else {
            for (int tt = 0; tt < SEG; tt += 8) {
#pragma unroll
                for (int u = 0; u < 8; ++u) {
                    PH_STEP(u, 1, mydpP, pA, pB, pC, pD, pE, eblP, dpP, rbP)
                    PH_STEP(u, 1, mydpQ, qA, qB, qC, qD, qE, eblQ, dpQ, rbQ)
                }
            }
        }
        STAGE_WRITE(buf ^ 1);
        buf ^= 1;
    }
    if (c < Kn) {
        const float v = half ? mydpQ : mydpP;
        dpfin[b * Kn + c] = v;
    }
#undef STAGE_LOAD
#undef STAGE_WRITE
}

// ---------------------------------------------------------------------------
// Recompute backpointers (round-0 proven, unchanged): task = (batch, segment);
// 32-lane half-wave per task, 8 tasks per 256-thread block. High occupancy
// hides all latencies; per-step math is bit-identical to crf_fwd (same add
// pairs, exact max), so argmax reproduces the exact backpointers.
// ---------------------------------------------------------------------------
__global__ __launch_bounds__(256) void crf_rec(
    const float* __restrict__ P, const float* __restrict__ T,
    const float* __restrict__ dpck, const int* __restrict__ lens,
    unsigned char* __restrict__ choice)
{
    const int tid = threadIdx.x;
    const int halfid = tid >> 5;
    const int c = tid & 31;
    const int cc = (c < Kn) ? c : (Kn - 1);
    const int task = blockIdx.x * 8 + halfid;   // < 16384
    const int b = task >> 5;
    const int seg = task & 31;
    const int t0 = seg * SEG;
    const int len = lens[b];
    if (t0 >= len) return;                      // rows never read by backtrace

    __shared__ float dp[8][32];
    __shared__ __align__(16) unsigned char cbuf[8][SEG * Kn];  // 8 x 1216

    float Trow[Kn];
#pragma unroll
    for (int p = 0; p < Kn; ++p) Trow[p] = T[cc * Kn + p];

    float mydp = (c < Kn) ? dpck[((unsigned)b * 32u + (unsigned)seg) * (unsigned)Kn + (unsigned)c]
                          : NEGV;
    dp[halfid][c] = mydp;

    const float* prow = P + (size_t)b * Ln * Kn + (size_t)t0 * Kn;

    // rolling emission prefetch (depth 8)
    float eb[8];
#pragma unroll
    for (int u = 0; u < 8; ++u) eb[u] = prow[u * Kn + cc];

    for (int tt = 0; tt < SEG; tt += 8) {
#pragma unroll
        for (int u = 0; u < 8; ++u) {
            const int t = t0 + tt + u;
            const float e = eb[u];
            const float* base_ = &dp[halfid][0];
            DP_CORE(base_)
            float nd = best + e;
            mydp = (t < len) ? nd : mydp;
            dp[halfid][c] = mydp;

            // first-index argmax (jnp.argmax tie-break), exact equality
            int arg = Kn - 1;
#pragma unroll
            for (int p = Kn - 2; p >= 0; --p)
                arg = (cand[p] == best) ? p : arg;
            if (c < Kn) cbuf[halfid][(tt + u) * Kn + c] = (unsigned char)arg;

            // prefetch emission for local step tt+u+8 (clamped in-bounds)
            int tn = tt + u + 8;
            int tloc = (t0 + tn < Ln) ? tn : (Ln - 1 - t0);
            eb[u] = prow[tloc * Kn + cc];
        }
    }
    // bulk flush this segment's backpointers (steps >= len garbage, unread)
    {
        const int4* s = (const int4*)&cbuf[halfid][0];
        int4* d = (int4*)(choice + (size_t)b * Ln * Kn + (size_t)t0 * Kn);
        for (int i = c; i < (SEG * Kn) / 16; i += 32) d[i] = s[i];
    }
}

// ---------------------------------------------------------------------------
// Backtrace: unchanged (exact integer function-composition scan).
// ---------------------------------------------------------------------------
__global__ __launch_bounds__(384, 1) void crf_bwd(
    const float* __restrict__ T, const unsigned char* __restrict__ choice,
    const float* __restrict__ dpfin, const int* __restrict__ lens,
    int* __restrict__ out)
{
    __shared__ unsigned char comp[Ln * Kn];   // 38912 B
    __shared__ int vchain[17];
    __shared__ int s_last, s_len;

    const int b = blockIdx.x;
    const int tid = threadIdx.x;

    {
        const int4* src = (const int4*)(choice + (size_t)b * Ln * Kn);
        int4* dst = (int4*)comp;
        for (int i = tid; i < (Ln * Kn) / 16; i += 384) dst[i] = src[i];
    }
    if (tid == 0) {
        s_len = lens[b];
        float bestv = dpfin[b * Kn + 0] + T[PAD_IDn * Kn + 0];
        int bl = 0;
        for (int ci = 1; ci < Kn; ++ci) {
            float v = dpfin[b * Kn + ci] + T[PAD_IDn * Kn + ci];
            if (v > bestv) { bestv = v; bl = ci; }
        }
        s_last = bl;
    }
    __syncthreads();
    const int len = s_len;

    // Phase 1: suffix-compose within each 128-step chunk, in place.
    {
        const int wv = tid >> 6;
        const int lane = tid & 63;
        const int ch = wv * 3 + lane / Kn;
        const int c = lane % Kn;
        if (lane < 3 * Kn && ch < 16) {
            int cur = c;
            const int tb = ch * 128 + 127;
            for (int i = 0; i < 128; ++i) {
                const int t = tb - i;
                int nv = comp[t * Kn + cur];   // cur <= 18 always: in-bounds
                cur = (t < len) ? nv : cur;
                comp[t * Kn + c] = cur;
            }
        }
    }
    __syncthreads();

    // Phase 2: chunk-boundary chain
    if (tid == 0) {
        int v = s_last;
        vchain[16] = v;
        for (int ch = 15; ch >= 0; --ch) {
            v = comp[ch * 128 * Kn + v];
            vchain[ch] = v;
        }
    }
    __syncthreads();

    // Phase 3: emit path
    const int last = s_last;
    int* orow = out + (size_t)b * Ln;
    for (int t = tid; t < Ln; t += 384) {
        int val;
        if (t >= len) {
            val = -1;
        } else if (t == Ln - 1) {
            val = last;
        } else {
            const int tp = t + 1;
            const int vc = vchain[(tp >> 7) + 1];
            val = comp[tp * Kn + vc];
        }
        orow[t] = val;
    }
}

// ---------------------------------------------------------------------------
extern "C" void kernel_launch(void* const* d_in, const int* in_sizes, int n_in,
                              void* d_out, int out_size, void* d_ws, size_t ws_size,
                              hipStream_t stream)
{
    const float* P    = (const float*)d_in[0];
    const float* T    = (const float*)d_in[1];
    const int*   mask = (const int*)d_in[2];
    int* out = (int*)d_out;

    // workspace layout — identical proven footprint (R1-R5)
    const size_t choice_bytes = (size_t)Bn * Ln * Kn;            // 19,922,944
    unsigned char* choice = (unsigned char*)d_ws;
    float* dpfin = (float*)((char*)d_ws + choice_bytes);         // 38,912 B
    int* lens = (int*)((char*)d_ws + choice_bytes + (size_t)Bn * Kn * 4);

    // dpck (1,245,184 B) lives in d_out (4 MB): written by crf_fwd, read by
    // crf_rec, then d_out is fully overwritten by crf_bwd. Stream-ordered.
    float* dpck = (float*)((char*)d_out + 2 * 1024 * 1024);

    crf_fwd<<<Bn / 2, 64, 0, stream>>>(P, T, mask, dpck, dpfin, lens);
    crf_rec<<<(Bn * 32) / 8, 256, 0, stream>>>(P, T, dpck, lens, choice);
    crf_bwd<<<Bn, 384, 0, stream>>>(T, choice, dpfin, lens, out);
}

// Round 8
// 393.499 us; speedup vs baseline: 1.3451x; 1.3360x over previous
//
#include <hip/hip_runtime.h>

#define Bn 512
#define Ln 2048
#define Kn 19
#define NEGV (-1000.0f)
#define START_IDn 17
#define PAD_IDn 18
#define SEG 64               // checkpoint / staging segment (steps)
#define PBYTES 79691776u     // 512*2048*19*4

// ---------------------------------------------------------------------------
// R13: fwd untouched (R5-exact, proven 238us floor: R6-R12 showed every
// alternative broadcast/pipeline is >= 280cy/step = issue + LDS round-trip).
// rec+bwd fused per-batch: one 1024-thread block per batch = 32 half-wave
// rec tasks (verbatim proven core) writing backpointers DIRECTLY into the
// comp[] LDS buffer bwd consumes — deletes the 20MB choice store + 20MB
// reload + one dispatch gap. bwd phases verbatim, phase 1 remapped to
// 16 waves x 1 chunk (19-lane chunk groups stay inside one wave => lockstep
// read-before-write preserved). dpck relocated to d_ws offset 0 (unused
// choice region; identical proven ws footprint) — avoids racing phase-3's
// d_out writes.
// ---------------------------------------------------------------------------

// per-step core (bit-exact, shared by fwd and rec): cand[p] = dp[p]+Trow[p],
// exact max tree.
#define DP_CORE(BASE)                                                          \
    float4 q0 = *(const float4*)((BASE) + 0);                                  \
    float4 q1 = *(const float4*)((BASE) + 4);                                  \
    float4 q2 = *(const float4*)((BASE) + 8);                                  \
    float4 q3 = *(const float4*)((BASE) + 12);                                 \
    float4 q4 = *(const float4*)((BASE) + 16); /* .w junk, unused */           \
    float cand[Kn];                                                            \
    cand[0]  = q0.x + Trow[0];  cand[1]  = q0.y + Trow[1];                     \
    cand[2]  = q0.z + Trow[2];  cand[3]  = q0.w + Trow[3];                     \
    cand[4]  = q1.x + Trow[4];  cand[5]  = q1.y + Trow[5];                     \
    cand[6]  = q1.z + Trow[6];  cand[7]  = q1.w + Trow[7];                     \
    cand[8]  = q2.x + Trow[8];  cand[9]  = q2.y + Trow[9];                     \
    cand[10] = q2.z + Trow[10]; cand[11] = q2.w + Trow[11];                    \
    cand[12] = q3.x + Trow[12]; cand[13] = q3.y + Trow[13];                    \
    cand[14] = q3.z + Trow[14]; cand[15] = q3.w + Trow[15];                    \
    cand[16] = q4.x + Trow[16]; cand[17] = q4.y + Trow[17];                    \
    cand[18] = q4.z + Trow[18];                                                \
    float m0 = fmaxf(fmaxf(cand[0],  cand[1]),  cand[2]);                      \
    float m1 = fmaxf(fmaxf(cand[3],  cand[4]),  cand[5]);                      \
    float m2 = fmaxf(fmaxf(cand[6],  cand[7]),  cand[8]);                      \
    float m3 = fmaxf(fmaxf(cand[9],  cand[10]), cand[11]);                     \
    float m4 = fmaxf(fmaxf(cand[12], cand[13]), cand[14]);                     \
    float m5 = fmaxf(fmaxf(cand[15], cand[16]), cand[17]);                     \
    float n0 = fmaxf(fmaxf(m0, m1), m2);                                       \
    float n1 = fmaxf(fmaxf(m3, m4), cand[18]);                                 \
    float best = fmaxf(fmaxf(n0, n1), m5);

// ---------------------------------------------------------------------------
// FWD: byte-identical to the proven 238us kernel (2 batches per wave).
// ---------------------------------------------------------------------------
__global__ __launch_bounds__(64, 1) void crf_fwd(
    const float* __restrict__ P, const float* __restrict__ T,
    const int* __restrict__ mask, float* __restrict__ dpck,
    float* __restrict__ dpfin, int* __restrict__ lens)
{
    const int lane = threadIdx.x;
    const int half = lane >> 5;
    const int c = lane & 31;
    const int b = blockIdx.x * 2 + half;
    const int cc = (c < Kn) ? c : (Kn - 1);

    float Trow[Kn];
#pragma unroll
    for (int p = 0; p < Kn; ++p) Trow[p] = T[cc * Kn + p];

    // length = popcount of contiguous-prefix mask row
    const int* mrow = mask + (size_t)b * Ln;
    int sum = 0;
#pragma unroll
    for (int j = 0; j < Ln / 128; ++j) {
        int4 v = *(const int4*)(mrow + j * 128 + c * 4);
        sum += v.x + v.y + v.z + v.w;
    }
#pragma unroll
    for (int k = 1; k < 32; k <<= 1) sum += __shfl_xor(sum, k, 64);
    const int len = sum;
    if (c == 0) lens[b] = len;
    const int lenO = __shfl_xor(len, 32, 64);
    int maxlen = len > lenO ? len : lenO;
    int lmin = len < lenO ? len : lenO;
    lmin = __builtin_amdgcn_readfirstlane(lmin);
    int mlen = (maxlen + (SEG - 1)) & ~(SEG - 1);
    mlen = __builtin_amdgcn_readfirstlane(mlen);

    __shared__ float dp[2][32];
    __shared__ float ebuf[2][2][1280];   // [buf][half]; 64*19=1216 used + pad

    float mydp = (c == START_IDn) ? 0.0f : NEGV;
    dp[half][c] = mydp;

    const unsigned bbyte = (unsigned)b * (Ln * Kn * 4u);
    const unsigned limit = PBYTES - 16;
    const char* Pc = (const char*)P;
    float4 r[10];

#define STAGE_LOAD(ci)                                                         \
    { unsigned base_ = bbyte + (unsigned)(ci) * 4864u + ((unsigned)c << 4);    \
      _Pragma("unroll")                                                        \
      for (int i_ = 0; i_ < 10; ++i_) {                                        \
          unsigned o_ = base_ + (unsigned)i_ * 512u;                           \
          if (o_ > limit) o_ = limit;                                          \
          r[i_] = *(const float4*)(Pc + o_);                                   \
      } }
#define STAGE_WRITE(nb)                                                        \
    { float* d_ = &ebuf[nb][half][(unsigned)c << 2];                           \
      _Pragma("unroll")                                                        \
      for (int i_ = 0; i_ < 10; ++i_) *(float4*)(d_ + i_ * 128) = r[i_]; }

    int buf = 0;
    STAGE_LOAD(0);
    STAGE_WRITE(0);

    for (int t0 = 0; t0 < mlen; t0 += SEG) {
        // checkpoint: DP entering step t0 (includes initial DP at t0=0)
        if (c < Kn)
            dpck[((unsigned)b * 32u + (unsigned)(t0 >> 6)) * (unsigned)Kn + (unsigned)c] = mydp;
        STAGE_LOAD((t0 >> 6) + 1);       // prefetch next segment's emissions
        const float* ebl = &ebuf[buf][half][0];

        if (t0 + SEG <= lmin) {
            // fast path: every step strictly below both lengths — no mask
            for (int tt = 0; tt < SEG; tt += 8) {
#pragma unroll
                for (int u = 0; u < 8; ++u) {
                    const float e = ebl[(tt + u) * Kn + cc];
                    const float* base_ = &dp[half][0];
                    DP_CORE(base_)
                    mydp = best + e;
                    dp[half][c] = mydp;
                }
            }
        } else {
            for (int tt = 0; tt < SEG; tt += 8) {
#pragma unroll
                for (int u = 0; u < 8; ++u) {
                    const int t = t0 + tt + u;
                    const float e = ebl[(tt + u) * Kn + cc];
                    const float* base_ = &dp[half][0];
                    DP_CORE(base_)
                    float nd = best + e;
                    mydp = (t < len) ? nd : mydp;   // frozen past sequence end
                    dp[half][c] = mydp;
                }
            }
        }
        STAGE_WRITE(buf ^ 1);
        buf ^= 1;
    }
    if (c < Kn) dpfin[b * Kn + c] = mydp;
#undef STAGE_LOAD
#undef STAGE_WRITE
}

// ---------------------------------------------------------------------------
// Fused rec+bwd: one block per batch. Phase R = 32 half-wave rec tasks
// (seg = halfid), bit-exact recompute from checkpoints, backpointers written
// straight into comp[] (LDS). Then the proven backtrace phases 1-3.
// ---------------------------------------------------------------------------
__global__ __launch_bounds__(1024, 1) void crf_recbwd(
    const float* __restrict__ P, const float* __restrict__ T,
    const float* __restrict__ dpck, const float* __restrict__ dpfin,
    const int* __restrict__ lens, int* __restrict__ out)
{
    const int b = blockIdx.x;
    const int tid = threadIdx.x;
    const int halfid = tid >> 5;                // 0..31 == segment index
    const int c = tid & 31;
    const int cc = (c < Kn) ? c : (Kn - 1);
    const int t0 = halfid * SEG;
    const int len = lens[b];

    __shared__ unsigned char comp[Ln * Kn];     // 38912 B: bp, then composed
    __shared__ float dp[32][32];                // per-segment DP round-trip
    __shared__ int vchain[17];
    __shared__ int s_last;

    // ---------------- Phase R: recompute backpointers into comp ------------
    if (t0 < len) {
        float Trow[Kn];
#pragma unroll
        for (int p = 0; p < Kn; ++p) Trow[p] = T[cc * Kn + p];

        float mydp = (c < Kn)
            ? dpck[((unsigned)b * 32u + (unsigned)halfid) * (unsigned)Kn + (unsigned)c]
            : NEGV;
        dp[halfid][c] = mydp;

        const float* prow = P + (size_t)b * Ln * Kn + (size_t)t0 * Kn;

        // rolling emission prefetch (depth 8)
        float eb[8];
#pragma unroll
        for (int u = 0; u < 8; ++u) eb[u] = prow[u * Kn + cc];

        for (int tt = 0; tt < SEG; tt += 8) {
#pragma unroll
            for (int u = 0; u < 8; ++u) {
                const int t = t0 + tt + u;
                const float e = eb[u];
                const float* base_ = &dp[halfid][0];
                DP_CORE(base_)
                float nd = best + e;
                mydp = (t < len) ? nd : mydp;
                dp[halfid][c] = mydp;

                // first-index argmax (jnp.argmax tie-break), exact equality
                int arg = Kn - 1;
#pragma unroll
                for (int p = Kn - 2; p >= 0; --p)
                    arg = (cand[p] == best) ? p : arg;
                if (c < Kn) comp[t * Kn + c] = (unsigned char)arg;

                // prefetch emission for local step tt+u+8 (clamped in-bounds)
                int tn = tt + u + 8;
                int tloc = (t0 + tn < Ln) ? tn : (Ln - 1 - t0);
                eb[u] = prow[tloc * Kn + cc];
            }
        }
    }
    // rows t >= len are uninitialized LDS: read-then-discarded below (values
    // never used as indices), exactly as the proven bwd handled garbage rows.

    if (tid == 0) {
        float bestv = dpfin[b * Kn + 0] + T[PAD_IDn * Kn + 0];
        int bl = 0;
        for (int ci = 1; ci < Kn; ++ci) {
            float v = dpfin[b * Kn + ci] + T[PAD_IDn * Kn + ci];
            if (v > bestv) { bestv = v; bl = ci; }
        }
        s_last = bl;
    }
    __syncthreads();

    // ---- Phase 1: suffix-compose within each 128-step chunk, in place.
    // 16 waves x 1 chunk; the 19 active lanes of a chunk share one wave =>
    // lockstep guarantees all reads of iteration i precede its writes.
    {
        const int wv = tid >> 6;                 // 0..15 == chunk
        const int lane2 = tid & 63;
        if (lane2 < Kn) {
            int cur = lane2;
            const int tb = wv * 128 + 127;
            for (int i = 0; i < 128; ++i) {
                const int t = tb - i;
                int nv = comp[t * Kn + cur];     // cur <= 18 always: in-bounds
                cur = (t < len) ? nv : cur;
                comp[t * Kn + lane2] = cur;
            }
        }
    }
    __syncthreads();

    // ---- Phase 2: chunk-boundary chain
    if (tid == 0) {
        int v = s_last;
        vchain[16] = v;
        for (int ch = 15; ch >= 0; --ch) {
            v = comp[ch * 128 * Kn + v];
            vchain[ch] = v;
        }
    }
    __syncthreads();

    // ---- Phase 3: emit path
    const int last = s_last;
    int* orow = out + (size_t)b * Ln;
    for (int t = tid; t < Ln; t += 1024) {
        int val;
        if (t >= len) {
            val = -1;
        } else if (t == Ln - 1) {
            val = last;
        } else {
            const int tp = t + 1;
            const int vc = vchain[(tp >> 7) + 1];
            val = comp[tp * Kn + vc];
        }
        orow[t] = val;
    }
}

// ---------------------------------------------------------------------------
extern "C" void kernel_launch(void* const* d_in, const int* in_sizes, int n_in,
                              void* d_out, int out_size, void* d_ws, size_t ws_size,
                              hipStream_t stream)
{
    const float* P    = (const float*)d_in[0];
    const float* T    = (const float*)d_in[1];
    const int*   mask = (const int*)d_in[2];
    int* out = (int*)d_out;

    // workspace layout — identical proven footprint (19,963,904 B). The old
    // choice region (19.92 MB at offset 0) is no longer streamed; dpck
    // (1,245,184 B) now lives at its head. dpfin/lens keep proven offsets.
    const size_t choice_bytes = (size_t)Bn * Ln * Kn;            // 19,922,944
    float* dpck  = (float*)d_ws;
    float* dpfin = (float*)((char*)d_ws + choice_bytes);         // 38,912 B
    int* lens = (int*)((char*)d_ws + choice_bytes + (size_t)Bn * Kn * 4);

    crf_fwd<<<Bn / 2, 64, 0, stream>>>(P, T, mask, dpck, dpfin, lens);
    crf_recbwd<<<Bn, 1024, 0, stream>>>(P, T, dpck, dpfin, lens, out);
}

// Round 9
// 377.575 us; speedup vs baseline: 1.4019x; 1.0422x over previous
//
#include <hip/hip_runtime.h>

#define Bn 512
#define Ln 2048
#define Kn 19
#define NEGV (-1000.0f)
#define START_IDn 17
#define PAD_IDn 18
#define SEG 64               // checkpoint / staging segment (steps)
#define PBYTES 79691776u     // 512*2048*19*4

// ---------------------------------------------------------------------------
// R14 = R13 with recbwd's rec phase regrouped 2x32-lane -> 3x21-lane segments
// per wave. The 5 uniform-address ds_read_b128 per DP step serve every group
// in the wave with ONE instruction, so carrying 3 segments instead of 2 cuts
// DS ops/CU by 31% (R13 post-mortem: rec phase is DS-throughput-bound at
// ~7 DS ops x ~12cy x 14.3K/CU). Block = 704 thr (11 waves; wave 10 carries
// 2 segs). dp rows padded to 20 floats (80B, b128-aligned; slot 19 junk ==
// today's q4.w). Same op order => bit-exact DP/argmax. fwd byte-identical to
// the proven 237.6us kernel; bwd phases 1-3 keep the proven mapping.
// ---------------------------------------------------------------------------

// per-step core (bit-exact, shared by fwd and rec): cand[p] = dp[p]+Trow[p],
// exact max tree.
#define DP_CORE(BASE)                                                          \
    float4 q0 = *(const float4*)((BASE) + 0);                                  \
    float4 q1 = *(const float4*)((BASE) + 4);                                  \
    float4 q2 = *(const float4*)((BASE) + 8);                                  \
    float4 q3 = *(const float4*)((BASE) + 12);                                 \
    float4 q4 = *(const float4*)((BASE) + 16); /* .w junk, unused */           \
    float cand[Kn];                                                            \
    cand[0]  = q0.x + Trow[0];  cand[1]  = q0.y + Trow[1];                     \
    cand[2]  = q0.z + Trow[2];  cand[3]  = q0.w + Trow[3];                     \
    cand[4]  = q1.x + Trow[4];  cand[5]  = q1.y + Trow[5];                     \
    cand[6]  = q1.z + Trow[6];  cand[7]  = q1.w + Trow[7];                     \
    cand[8]  = q2.x + Trow[8];  cand[9]  = q2.y + Trow[9];                     \
    cand[10] = q2.z + Trow[10]; cand[11] = q2.w + Trow[11];                    \
    cand[12] = q3.x + Trow[12]; cand[13] = q3.y + Trow[13];                    \
    cand[14] = q3.z + Trow[14]; cand[15] = q3.w + Trow[15];                    \
    cand[16] = q4.x + Trow[16]; cand[17] = q4.y + Trow[17];                    \
    cand[18] = q4.z + Trow[18];                                                \
    float m0 = fmaxf(fmaxf(cand[0],  cand[1]),  cand[2]);                      \
    float m1 = fmaxf(fmaxf(cand[3],  cand[4]),  cand[5]);                      \
    float m2 = fmaxf(fmaxf(cand[6],  cand[7]),  cand[8]);                      \
    float m3 = fmaxf(fmaxf(cand[9],  cand[10]), cand[11]);                     \
    float m4 = fmaxf(fmaxf(cand[12], cand[13]), cand[14]);                     \
    float m5 = fmaxf(fmaxf(cand[15], cand[16]), cand[17]);                     \
    float n0 = fmaxf(fmaxf(m0, m1), m2);                                       \
    float n1 = fmaxf(fmaxf(m3, m4), cand[18]);                                 \
    float best = fmaxf(fmaxf(n0, n1), m5);

// ---------------------------------------------------------------------------
// FWD: byte-identical to the proven 237.6us kernel (2 batches per wave).
// ---------------------------------------------------------------------------
__global__ __launch_bounds__(64, 1) void crf_fwd(
    const float* __restrict__ P, const float* __restrict__ T,
    const int* __restrict__ mask, float* __restrict__ dpck,
    float* __restrict__ dpfin, int* __restrict__ lens)
{
    const int lane = threadIdx.x;
    const int half = lane >> 5;
    const int c = lane & 31;
    const int b = blockIdx.x * 2 + half;
    const int cc = (c < Kn) ? c : (Kn - 1);

    float Trow[Kn];
#pragma unroll
    for (int p = 0; p < Kn; ++p) Trow[p] = T[cc * Kn + p];

    // length = popcount of contiguous-prefix mask row
    const int* mrow = mask + (size_t)b * Ln;
    int sum = 0;
#pragma unroll
    for (int j = 0; j < Ln / 128; ++j) {
        int4 v = *(const int4*)(mrow + j * 128 + c * 4);
        sum += v.x + v.y + v.z + v.w;
    }
#pragma unroll
    for (int k = 1; k < 32; k <<= 1) sum += __shfl_xor(sum, k, 64);
    const int len = sum;
    if (c == 0) lens[b] = len;
    const int lenO = __shfl_xor(len, 32, 64);
    int maxlen = len > lenO ? len : lenO;
    int lmin = len < lenO ? len : lenO;
    lmin = __builtin_amdgcn_readfirstlane(lmin);
    int mlen = (maxlen + (SEG - 1)) & ~(SEG - 1);
    mlen = __builtin_amdgcn_readfirstlane(mlen);

    __shared__ float dp[2][32];
    __shared__ float ebuf[2][2][1280];   // [buf][half]; 64*19=1216 used + pad

    float mydp = (c == START_IDn) ? 0.0f : NEGV;
    dp[half][c] = mydp;

    const unsigned bbyte = (unsigned)b * (Ln * Kn * 4u);
    const unsigned limit = PBYTES - 16;
    const char* Pc = (const char*)P;
    float4 r[10];

#define STAGE_LOAD(ci)                                                         \
    { unsigned base_ = bbyte + (unsigned)(ci) * 4864u + ((unsigned)c << 4);    \
      _Pragma("unroll")                                                        \
      for (int i_ = 0; i_ < 10; ++i_) {                                        \
          unsigned o_ = base_ + (unsigned)i_ * 512u;                           \
          if (o_ > limit) o_ = limit;                                          \
          r[i_] = *(const float4*)(Pc + o_);                                   \
      } }
#define STAGE_WRITE(nb)                                                        \
    { float* d_ = &ebuf[nb][half][(unsigned)c << 2];                           \
      _Pragma("unroll")                                                        \
      for (int i_ = 0; i_ < 10; ++i_) *(float4*)(d_ + i_ * 128) = r[i_]; }

    int buf = 0;
    STAGE_LOAD(0);
    STAGE_WRITE(0);

    for (int t0 = 0; t0 < mlen; t0 += SEG) {
        // checkpoint: DP entering step t0 (includes initial DP at t0=0)
        if (c < Kn)
            dpck[((unsigned)b * 32u + (unsigned)(t0 >> 6)) * (unsigned)Kn + (unsigned)c] = mydp;
        STAGE_LOAD((t0 >> 6) + 1);       // prefetch next segment's emissions
        const float* ebl = &ebuf[buf][half][0];

        if (t0 + SEG <= lmin) {
            // fast path: every step strictly below both lengths — no mask
            for (int tt = 0; tt < SEG; tt += 8) {
#pragma unroll
                for (int u = 0; u < 8; ++u) {
                    const float e = ebl[(tt + u) * Kn + cc];
                    const float* base_ = &dp[half][0];
                    DP_CORE(base_)
                    mydp = best + e;
                    dp[half][c] = mydp;
                }
            }
        } else {
            for (int tt = 0; tt < SEG; tt += 8) {
#pragma unroll
                for (int u = 0; u < 8; ++u) {
                    const int t = t0 + tt + u;
                    const float e = ebl[(tt + u) * Kn + cc];
                    const float* base_ = &dp[half][0];
                    DP_CORE(base_)
                    float nd = best + e;
                    mydp = (t < len) ? nd : mydp;   // frozen past sequence end
                    dp[half][c] = mydp;
                }
            }
        }
        STAGE_WRITE(buf ^ 1);
        buf ^= 1;
    }
    if (c < Kn) dpfin[b * Kn + c] = mydp;
#undef STAGE_LOAD
#undef STAGE_WRITE
}

// ---------------------------------------------------------------------------
// Fused rec+bwd: one 704-thread block (11 waves) per batch. Phase R = 32
// segments in 21-lane groups, 3 per wave (wave 10 carries 2); bit-exact
// recompute from checkpoints, backpointers straight into comp[] (LDS).
// Then the proven backtrace phases 1-3.
// ---------------------------------------------------------------------------
__global__ __launch_bounds__(704, 1) void crf_recbwd(
    const float* __restrict__ P, const float* __restrict__ T,
    const float* __restrict__ dpck, const float* __restrict__ dpfin,
    const int* __restrict__ lens, int* __restrict__ out)
{
    const int b = blockIdx.x;
    const int tid = threadIdx.x;
    const int len = lens[b];

    __shared__ unsigned char comp[Ln * Kn];     // 38912 B: bp, then composed
    __shared__ float dp[32][20];                // 20-float rows: 80B, b128-ok
    __shared__ int vchain[17];
    __shared__ int s_last;

    // ---------------- Phase R: recompute backpointers into comp ------------
    {
        const int w = tid >> 6;                 // wave 0..10
        const int lane64 = tid & 63;
        const int g = lane64 / 21;              // group 0..3 (3 = idle lane 63)
        const int c = lane64 - g * 21;          // 0..20 within group
        const int seg0 = w * 3 + g;             // 0..32
        const bool gvalid = (g < 3) && (seg0 < 32);
        const int seg = gvalid ? seg0 : 31;     // clamped for safe addressing
        const int cc = (c < Kn) ? c : (Kn - 1);
        const int t0 = seg * SEG;
        const bool active = gvalid && (t0 < len);

        float Trow[Kn];
#pragma unroll
        for (int p = 0; p < Kn; ++p) Trow[p] = T[cc * Kn + p];

        float mydp = (active && c < Kn)
            ? dpck[((unsigned)b * 32u + (unsigned)seg) * (unsigned)Kn + (unsigned)c]
            : NEGV;
        if (active && c < Kn) dp[seg][c] = mydp;

        const float* prow = P + (size_t)b * Ln * Kn + (size_t)t0 * Kn;

        // rolling emission prefetch (depth 8)
        float eb[8];
#pragma unroll
        for (int u = 0; u < 8; ++u) eb[u] = prow[u * Kn + cc];

        for (int tt = 0; tt < SEG; tt += 8) {
#pragma unroll
            for (int u = 0; u < 8; ++u) {
                const int t = t0 + tt + u;
                const float e = eb[u];
                const float* base_ = &dp[seg][0];
                DP_CORE(base_)
                float nd = best + e;
                mydp = (t < len) ? nd : mydp;
                if (active && c < Kn) dp[seg][c] = mydp;

                // first-index argmax (jnp.argmax tie-break), exact equality
                int arg = Kn - 1;
#pragma unroll
                for (int p = Kn - 2; p >= 0; --p)
                    arg = (cand[p] == best) ? p : arg;
                if (active && c < Kn) comp[t * Kn + c] = (unsigned char)arg;

                // prefetch emission for local step tt+u+8 (clamped in-bounds)
                int tn = tt + u + 8;
                int tloc = (t0 + tn < Ln) ? tn : (Ln - 1 - t0);
                eb[u] = prow[tloc * Kn + cc];
            }
        }
    }
    // rows t >= len are uninitialized LDS: read-then-discarded below (values
    // never used as indices), exactly as the proven bwd handled garbage rows.

    if (tid == 0) {
        float bestv = dpfin[b * Kn + 0] + T[PAD_IDn * Kn + 0];
        int bl = 0;
        for (int ci = 1; ci < Kn; ++ci) {
            float v = dpfin[b * Kn + ci] + T[PAD_IDn * Kn + ci];
            if (v > bestv) { bestv = v; bl = ci; }
        }
        s_last = bl;
    }
    __syncthreads();

    // ---- Phase 1: suffix-compose within each 128-step chunk, in place.
    // Proven mapping: 3 chunk-groups of 19 lanes per wave; chunk groups never
    // cross a wave => lockstep read-before-write preserved.
    {
        const int wv = tid >> 6;
        const int lane2 = tid & 63;
        const int ch = wv * 3 + lane2 / Kn;
        const int c2 = lane2 % Kn;
        if (lane2 < 3 * Kn && ch < 16) {
            int cur = c2;
            const int tb = ch * 128 + 127;
            for (int i = 0; i < 128; ++i) {
                const int t = tb - i;
                int nv = comp[t * Kn + cur];     // cur <= 18 always: in-bounds
                cur = (t < len) ? nv : cur;
                comp[t * Kn + c2] = cur;
            }
        }
    }
    __syncthreads();

    // ---- Phase 2: chunk-boundary chain
    if (tid == 0) {
        int v = s_last;
        vchain[16] = v;
        for (int ch = 15; ch >= 0; --ch) {
            v = comp[ch * 128 * Kn + v];
            vchain[ch] = v;
        }
    }
    __syncthreads();

    // ---- Phase 3: emit path
    const int last = s_last;
    int* orow = out + (size_t)b * Ln;
    for (int t = tid; t < Ln; t += 704) {
        int val;
        if (t >= len) {
            val = -1;
        } else if (t == Ln - 1) {
            val = last;
        } else {
            const int tp = t + 1;
            const int vc = vchain[(tp >> 7) + 1];
            val = comp[tp * Kn + vc];
        }
        orow[t] = val;
    }
}

// ---------------------------------------------------------------------------
extern "C" void kernel_launch(void* const* d_in, const int* in_sizes, int n_in,
                              void* d_out, int out_size, void* d_ws, size_t ws_size,
                              hipStream_t stream)
{
    const float* P    = (const float*)d_in[0];
    const float* T    = (const float*)d_in[1];
    const int*   mask = (const int*)d_in[2];
    int* out = (int*)d_out;

    // workspace layout — identical proven footprint (19,963,904 B). dpck
    // (1,245,184 B) at ws head (old choice region); dpfin/lens proven offsets.
    const size_t choice_bytes = (size_t)Bn * Ln * Kn;            // 19,922,944
    float* dpck  = (float*)d_ws;
    float* dpfin = (float*)((char*)d_ws + choice_bytes);         // 38,912 B
    int* lens = (int*)((char*)d_ws + choice_bytes + (size_t)Bn * Kn * 4);

    crf_fwd<<<Bn / 2, 64, 0, stream>>>(P, T, mask, dpck, dpfin, lens);
    crf_recbwd<<<Bn, 704, 0, stream>>>(P, T, dpck, dpfin, lens, out);
}